// Round 3
// baseline (306.310 us; speedup 1.0000x reference)
//
#include <hip/hip_runtime.h>
#include <stdint.h>
#include <math.h>

// Problem constants
#define BB   1024
#define TT   197
#define SS   196
#define DD   64
#define MM   200704   // BB*SS   (outputs per side)
#define GG   201728   // BB*TT   (param rows per table)
#define MBLK 1576     // GG/128 MLP blocks per side
#define NBLK (1024 + 2*MBLK)   // fused grid = 4176

// ---------------- Threefry2x32 (exact JAX rolled variant) ----------------
static __host__ __device__ inline uint32_t rotl_(uint32_t x, int r) {
  return (x << r) | (x >> (32 - r));
}

static __host__ __device__ inline void tf2x32(uint32_t k0, uint32_t k1,
                                              uint32_t& x0, uint32_t& x1) {
  uint32_t ks2 = k0 ^ k1 ^ 0x1BD11BDAu;
  x0 += k0; x1 += k1;
  x0 += x1; x1 = rotl_(x1,13); x1 ^= x0;
  x0 += x1; x1 = rotl_(x1,15); x1 ^= x0;
  x0 += x1; x1 = rotl_(x1,26); x1 ^= x0;
  x0 += x1; x1 = rotl_(x1, 6); x1 ^= x0;
  x0 += k1;  x1 += ks2 + 1u;
  x0 += x1; x1 = rotl_(x1,17); x1 ^= x0;
  x0 += x1; x1 = rotl_(x1,29); x1 ^= x0;
  x0 += x1; x1 = rotl_(x1,16); x1 ^= x0;
  x0 += x1; x1 = rotl_(x1,24); x1 ^= x0;
  x0 += ks2; x1 += k0 + 2u;
  x0 += x1; x1 = rotl_(x1,13); x1 ^= x0;
  x0 += x1; x1 = rotl_(x1,15); x1 ^= x0;
  x0 += x1; x1 = rotl_(x1,26); x1 ^= x0;
  x0 += x1; x1 = rotl_(x1, 6); x1 ^= x0;
  x0 += k0;  x1 += k1 + 3u;
  x0 += x1; x1 = rotl_(x1,17); x1 ^= x0;
  x0 += x1; x1 = rotl_(x1,29); x1 ^= x0;
  x0 += x1; x1 = rotl_(x1,16); x1 ^= x0;
  x0 += x1; x1 = rotl_(x1,24); x1 ^= x0;
  x0 += k1;  x1 += ks2 + 4u;
  x0 += x1; x1 = rotl_(x1,13); x1 ^= x0;
  x0 += x1; x1 = rotl_(x1,15); x1 ^= x0;
  x0 += x1; x1 = rotl_(x1,26); x1 ^= x0;
  x0 += x1; x1 = rotl_(x1, 6); x1 ^= x0;
  x0 += ks2; x1 += k0 + 5u;
}

// XLA ErfInv (float32 Giles polynomial), exact non-contracted rounding.
static __device__ inline float erfinv_xla(float x) {
  float w = -log1pf(-__fmul_rn(x, x));
  float p;
  if (w < 5.0f) {
    w = __fsub_rn(w, 2.5f);
    p = 2.81022636e-08f;
    p = __fadd_rn(__fmul_rn(p, w), 3.43273939e-07f);
    p = __fadd_rn(__fmul_rn(p, w), -3.5233877e-06f);
    p = __fadd_rn(__fmul_rn(p, w), -4.39150654e-06f);
    p = __fadd_rn(__fmul_rn(p, w), 0.00021858087f);
    p = __fadd_rn(__fmul_rn(p, w), -0.00125372503f);
    p = __fadd_rn(__fmul_rn(p, w), -0.00417768164f);
    p = __fadd_rn(__fmul_rn(p, w), 0.246640727f);
    p = __fadd_rn(__fmul_rn(p, w), 1.50140941f);
  } else {
    w = __fsub_rn(sqrtf(w), 3.0f);
    p = -0.000200214257f;
    p = __fadd_rn(__fmul_rn(p, w), 0.000100950558f);
    p = __fadd_rn(__fmul_rn(p, w), 0.00134934322f);
    p = __fadd_rn(__fmul_rn(p, w), -0.00367342844f);
    p = __fadd_rn(__fmul_rn(p, w), 0.00573950773f);
    p = __fadd_rn(__fmul_rn(p, w), -0.0076224613f);
    p = __fadd_rn(__fmul_rn(p, w), 0.00943887047f);
    p = __fadd_rn(__fmul_rn(p, w), 1.00167406f);
    p = __fadd_rn(__fmul_rn(p, w), 2.83297682f);
  }
  return __fmul_rn(p, x);
}

// eps[e] of jax.random.normal under jax_threefry_partitionable=True:
// per-element counter PRF, counter (hi=0, lo=e), draw = x0out ^ x1out.
static __device__ inline float jax_normal_elem(uint32_t k0, uint32_t k1, uint32_t e) {
  uint32_t c0 = 0u, c1 = e;
  tf2x32(k0, k1, c0, c1);
  uint32_t bits = c0 ^ c1;
  float f = __fsub_rn(__uint_as_float((bits >> 9) | 0x3F800000u), 1.0f); // [0,1)
  const float lo = -0.99999994f;
  float u = fmaxf(lo, __fadd_rn(__fmul_rn(f, 2.0f), lo));
  return __fmul_rn(1.41421356237309515f, erfinv_xla(u));
}

static __device__ inline float softplus_(float x) {
  return __fadd_rn(fmaxf(x, 0.0f), log1pf(expf(-fabsf(x))));
}

static __device__ inline float sigmoid_(float x) {
  if (x >= 0.0f) return 1.0f / (1.0f + expf(-x));
  float e = expf(x);
  return e / (1.0f + e);
}

// ---------------- Fused producer kernel: argmax + both MLPs ----------------
// Block roles interleaved 1:3 (A:M) so every CU carries both a BW-streaming
// argmax block and VALU-bound MLP blocks concurrently.
union SmemU {
  struct {
    float XT[64][128];
    float W1s[64][64];
    float W2s[64][4];
    float b1s[64];
    float b2s[4];
  } mlp;
  struct {
    float scv[4][256];
    int   sci[4][256];
  } amx;
};

__global__ __launch_bounds__(256) void fused_kernel(
    const float* __restrict__ sim,
    const float* __restrict__ post, const float* __restrict__ image,
    const float* __restrict__ tW1, const float* __restrict__ tb1,
    const float* __restrict__ tW2, const float* __restrict__ tb2,
    const float* __restrict__ iW1, const float* __restrict__ ib1,
    const float* __restrict__ iW2, const float* __restrict__ ib2,
    int* __restrict__ idx_p, int* __restrict__ idx_i,
    float4* __restrict__ params_t, float4* __restrict__ params_i) {
  __shared__ SmemU sm;
  int bid = blockIdx.x;
  int tid = threadIdx.x;

  // ---- role decode: bid<4096: every 4th block is argmax; tail is MLP ----
  bool is_amx;
  int aid = 0, mid = 0;
  if (bid < 4096) {
    if ((bid & 3) == 0) { is_amx = true; aid = bid >> 2; }
    else { is_amx = false; mid = bid - 1 - (bid >> 2); }
  } else {
    is_amx = false; mid = bid - 1024;
  }

  if (is_amx) {
    // ================= argmax over sim[aid, 1:, 1:] =================
    int wave = tid >> 6, lane = tid & 63;
    const float* Smat = sim + (size_t)aid * (TT * TT);

    float cval[4] = {-INFINITY, -INFINITY, -INFINITY, -INFINITY};
    int   cidx[4] = {0, 0, 0, 0};

    for (int t = wave; t < SS; t += 4) {
      const float* row = Smat + (size_t)(t + 1) * TT + 1;
      float v0 = row[lane];
      float v1 = row[lane + 64];
      float v2 = row[lane + 128];
      float v3 = (lane < 4) ? row[lane + 192] : -INFINITY;

      float bv = v0; int bj = lane;
      if (v1 > bv) { bv = v1; bj = lane + 64; }
      if (v2 > bv) { bv = v2; bj = lane + 128; }
      if (v3 > bv) { bv = v3; bj = lane + 192; }
      #pragma unroll
      for (int off = 32; off >= 1; off >>= 1) {
        float ov = __shfl_xor(bv, off);
        int   oj = __shfl_xor(bj, off);
        if (ov > bv || (ov == bv && oj < bj)) { bv = ov; bj = oj; }
      }
      if (lane == 0) idx_p[(size_t)aid * SS + t] = bj;

      if (v0 > cval[0]) { cval[0] = v0; cidx[0] = t; }
      if (v1 > cval[1]) { cval[1] = v1; cidx[1] = t; }
      if (v2 > cval[2]) { cval[2] = v2; cidx[2] = t; }
      if (v3 > cval[3]) { cval[3] = v3; cidx[3] = t; }
    }

    #pragma unroll
    for (int q = 0; q < 4; ++q) {
      int c = lane + 64 * q;
      sm.amx.scv[wave][c] = cval[q];
      sm.amx.sci[wave][c] = cidx[q];
    }
    __syncthreads();
    if (tid < SS) {
      float bv = sm.amx.scv[0][tid]; int bt = sm.amx.sci[0][tid];
      #pragma unroll
      for (int w = 1; w < 4; ++w) {
        float v = sm.amx.scv[w][tid]; int t2 = sm.amx.sci[w][tid];
        if (v > bv || (v == bv && t2 < bt)) { bv = v; bt = t2; }
      }
      idx_i[(size_t)aid * SS + tid] = bt;
    }
    return;
  }

  // ================= MLP: 128 rows of one side =================
  const float* X;  const float *W1, *B1, *W2, *B2;  float4* params;
  int blk;
  if (mid < MBLK) { X = post;  W1 = tW1; B1 = tb1; W2 = tW2; B2 = tb2; params = params_t; blk = mid; }
  else            { X = image; W1 = iW1; B1 = ib1; W2 = iW2; B2 = ib2; params = params_i; blk = mid - MBLK; }
  size_t g0 = (size_t)blk * 128;

  {
    const float4* w4 = (const float4*)W1;
    float4* s4 = (float4*)&sm.mlp.W1s[0][0];
    #pragma unroll
    for (int i = 0; i < 4; ++i) s4[tid + 256 * i] = w4[tid + 256 * i];
  }
  if (tid < 64) {
    ((float4*)&sm.mlp.W2s[0][0])[tid] = ((const float4*)W2)[tid];
    sm.mlp.b1s[tid] = B1[tid];
  }
  if (tid < 4) sm.mlp.b2s[tid] = B2[tid];

  {
    int r = tid & 127, kh = tid >> 7;
    const float4* src = (const float4*)(X + (g0 + (size_t)r) * 64 + kh * 32);
    #pragma unroll
    for (int q = 0; q < 8; ++q) {
      float4 v = src[q];
      int k0 = kh * 32 + q * 4;
      sm.mlp.XT[k0 + 0][r] = v.x; sm.mlp.XT[k0 + 1][r] = v.y;
      sm.mlp.XT[k0 + 2][r] = v.z; sm.mlp.XT[k0 + 3][r] = v.w;
    }
  }
  __syncthreads();

  int tr = tid >> 3, tc = tid & 7;
  int r0 = tr * 4, c0 = tc * 8;

  float acc[4][8];
  #pragma unroll
  for (int i = 0; i < 4; ++i)
    #pragma unroll
    for (int j = 0; j < 8; ++j) acc[i][j] = sm.mlp.b1s[c0 + j];

  #pragma unroll 4
  for (int k = 0; k < 64; ++k) {
    float4 xv = *(const float4*)&sm.mlp.XT[k][r0];
    float4 wa = *(const float4*)&sm.mlp.W1s[k][c0];
    float4 wb = *(const float4*)&sm.mlp.W1s[k][c0 + 4];
    float xr[4] = {xv.x, xv.y, xv.z, xv.w};
    float wc[8] = {wa.x, wa.y, wa.z, wa.w, wb.x, wb.y, wb.z, wb.w};
    #pragma unroll
    for (int i = 0; i < 4; ++i)
      #pragma unroll
      for (int j = 0; j < 8; ++j)
        acc[i][j] = fmaf(xr[i], wc[j], acc[i][j]);
  }

  #pragma unroll
  for (int i = 0; i < 4; ++i)
    #pragma unroll
    for (int j = 0; j < 8; ++j) acc[i][j] = fmaxf(acc[i][j], 0.0f);

  float p[4][4] = {{0,0,0,0},{0,0,0,0},{0,0,0,0},{0,0,0,0}};
  #pragma unroll
  for (int j = 0; j < 8; ++j) {
    float4 w2 = *(const float4*)&sm.mlp.W2s[c0 + j][0];
    #pragma unroll
    for (int i = 0; i < 4; ++i) {
      p[i][0] = fmaf(acc[i][j], w2.x, p[i][0]);
      p[i][1] = fmaf(acc[i][j], w2.y, p[i][1]);
      p[i][2] = fmaf(acc[i][j], w2.z, p[i][2]);
      p[i][3] = fmaf(acc[i][j], w2.w, p[i][3]);
    }
  }
  #pragma unroll
  for (int off = 1; off < 8; off <<= 1)
    #pragma unroll
    for (int i = 0; i < 4; ++i)
      #pragma unroll
      for (int c = 0; c < 4; ++c)
        p[i][c] += __shfl_xor(p[i][c], off);

  if (tc == 0) {
    #pragma unroll
    for (int i = 0; i < 4; ++i) {
      float m0 = p[i][0] + sm.mlp.b2s[0];
      float m1 = p[i][1] + sm.mlp.b2s[1];
      float s0 = __fadd_rn(softplus_(p[i][2] + sm.mlp.b2s[2]), 1e-07f);
      float s1 = __fadd_rn(softplus_(p[i][3] + sm.mlp.b2s[3]), 1e-07f);
      params[g0 + r0 + i] = make_float4(m0, m1, s0, s1);
    }
  }
}

// ---------------- Kernel 2: gather params, sample eps, log-prob diff ----------------
__global__ __launch_bounds__(256) void combine_kernel(
    const int* __restrict__ idx_p, const int* __restrict__ idx_i,
    const float4* __restrict__ params_t, const float4* __restrict__ params_i,
    float* __restrict__ out,
    uint32_t k1a, uint32_t k1b, uint32_t k2a, uint32_t k2b) {
  int id = blockIdx.x * 256 + threadIdx.x;
  int side = (id >= MM) ? 1 : 0;             // wave-uniform (MM % 256 == 0)
  int m = id - side * MM;
  int b = m / SS;
  int t = m - b * SS;

  float4 pa, pb;
  uint32_t ka, kb;
  if (!side) {
    pa = params_t[(size_t)b * TT + 1 + t];
    pb = params_i[(size_t)b * TT + idx_p[m]];
    ka = k1a; kb = k1b;
  } else {
    pa = params_i[(size_t)b * TT + 1 + t];
    pb = params_t[(size_t)b * TT + idx_i[m]];
    ka = k2a; kb = k2b;
  }

  uint32_t e0 = 2u * (uint32_t)m;
  float eps0 = jax_normal_elem(ka, kb, e0);
  float eps1 = jax_normal_elem(ka, kb, e0 + 1u);

  float z0 = __fadd_rn(pa.x, __fmul_rn(pa.z, eps0));
  float z1 = __fadd_rn(pa.y, __fmul_rn(pa.w, eps1));

  const float HLOG2PI = 0.91893853320467274f;
  float ea0 = __fsub_rn(z0, pa.x) / pa.z;
  float ea1 = __fsub_rn(z1, pa.y) / pa.w;
  float eb0 = __fsub_rn(z0, pb.x) / pb.z;
  float eb1 = __fsub_rn(z1, pb.y) / pb.w;

  float la0 = __fsub_rn(__fsub_rn(__fmul_rn(-0.5f, __fmul_rn(ea0, ea0)), logf(pa.z)), HLOG2PI);
  float la1 = __fsub_rn(__fsub_rn(__fmul_rn(-0.5f, __fmul_rn(ea1, ea1)), logf(pa.w)), HLOG2PI);
  float lb0 = __fsub_rn(__fsub_rn(__fmul_rn(-0.5f, __fmul_rn(eb0, eb0)), logf(pb.z)), HLOG2PI);
  float lb1 = __fsub_rn(__fsub_rn(__fmul_rn(-0.5f, __fmul_rn(eb1, eb1)), logf(pb.w)), HLOG2PI);
  float lpa = __fadd_rn(la0, la1);
  float lpb = __fadd_rn(lb0, lb1);

  out[id] = sigmoid_(sigmoid_(__fsub_rn(lpa, lpb)));
}

// ---------------- Launch ----------------
extern "C" void kernel_launch(void* const* d_in, const int* in_sizes, int n_in,
                              void* d_out, int out_size, void* d_ws, size_t ws_size,
                              hipStream_t stream) {
  const float* post  = (const float*)d_in[0];
  const float* image = (const float*)d_in[1];
  const float* sim   = (const float*)d_in[2];
  const float* tW1 = (const float*)d_in[3];
  const float* tb1 = (const float*)d_in[4];
  const float* tW2 = (const float*)d_in[5];
  const float* tb2 = (const float*)d_in[6];
  const float* iW1 = (const float*)d_in[7];
  const float* ib1 = (const float*)d_in[8];
  const float* iW2 = (const float*)d_in[9];
  const float* ib2 = (const float*)d_in[10];
  float* out = (float*)d_out;

  int* idx_p = (int*)d_ws;
  int* idx_i = idx_p + MM;
  float4* params_t = (float4*)(idx_i + MM);       // GG float4s
  float4* params_i = params_t + GG;

  // jax.random.split(key(42)) under threefry_partitionable:
  // child i = full 64-bit PRF output at counter (hi=0, lo=i).
  uint32_t k1a = 0, k1b = 0; tf2x32(0u, 42u, k1a, k1b);   // child 0
  uint32_t k2a = 0, k2b = 1; tf2x32(0u, 42u, k2a, k2b);   // child 1

  fused_kernel<<<dim3(NBLK), dim3(256), 0, stream>>>(
      sim, post, image, tW1, tb1, tW2, tb2, iW1, ib1, iW2, ib2,
      idx_p, idx_i, params_t, params_i);
  combine_kernel<<<dim3((2 * MM) / 256), dim3(256), 0, stream>>>(
      idx_p, idx_i, params_t, params_i, out, k1a, k1b, k2a, k2b);
}

// Round 5
// 150.560 us; speedup vs baseline: 2.0345x; 2.0345x over previous
//
#include <hip/hip_runtime.h>
#include <stdint.h>
#include <math.h>

// Problem constants
#define BB   1024
#define TT   197
#define SS   196
#define DD   64
#define MM   200704   // BB*SS   (outputs per side)
#define GG   201728   // BB*TT   (param rows per table)

// ---------------- Threefry2x32 (exact JAX rolled variant) ----------------
static __host__ __device__ inline uint32_t rotl_(uint32_t x, int r) {
  return (x << r) | (x >> (32 - r));
}

static __host__ __device__ inline void tf2x32(uint32_t k0, uint32_t k1,
                                              uint32_t& x0, uint32_t& x1) {
  uint32_t ks2 = k0 ^ k1 ^ 0x1BD11BDAu;
  x0 += k0; x1 += k1;
  x0 += x1; x1 = rotl_(x1,13); x1 ^= x0;
  x0 += x1; x1 = rotl_(x1,15); x1 ^= x0;
  x0 += x1; x1 = rotl_(x1,26); x1 ^= x0;
  x0 += x1; x1 = rotl_(x1, 6); x1 ^= x0;
  x0 += k1;  x1 += ks2 + 1u;
  x0 += x1; x1 = rotl_(x1,17); x1 ^= x0;
  x0 += x1; x1 = rotl_(x1,29); x1 ^= x0;
  x0 += x1; x1 = rotl_(x1,16); x1 ^= x0;
  x0 += x1; x1 = rotl_(x1,24); x1 ^= x0;
  x0 += ks2; x1 += k0 + 2u;
  x0 += x1; x1 = rotl_(x1,13); x1 ^= x0;
  x0 += x1; x1 = rotl_(x1,15); x1 ^= x0;
  x0 += x1; x1 = rotl_(x1,26); x1 ^= x0;
  x0 += x1; x1 = rotl_(x1, 6); x1 ^= x0;
  x0 += k0;  x1 += k1 + 3u;
  x0 += x1; x1 = rotl_(x1,17); x1 ^= x0;
  x0 += x1; x1 = rotl_(x1,29); x1 ^= x0;
  x0 += x1; x1 = rotl_(x1,16); x1 ^= x0;
  x0 += x1; x1 = rotl_(x1,24); x1 ^= x0;
  x0 += k1;  x1 += ks2 + 4u;
  x0 += x1; x1 = rotl_(x1,13); x1 ^= x0;
  x0 += x1; x1 = rotl_(x1,15); x1 ^= x0;
  x0 += x1; x1 = rotl_(x1,26); x1 ^= x0;
  x0 += x1; x1 = rotl_(x1, 6); x1 ^= x0;
  x0 += ks2; x1 += k0 + 5u;
}

// XLA ErfInv (float32 Giles polynomial), exact non-contracted rounding.
static __device__ inline float erfinv_xla(float x) {
  float w = -log1pf(-__fmul_rn(x, x));
  float p;
  if (w < 5.0f) {
    w = __fsub_rn(w, 2.5f);
    p = 2.81022636e-08f;
    p = __fadd_rn(__fmul_rn(p, w), 3.43273939e-07f);
    p = __fadd_rn(__fmul_rn(p, w), -3.5233877e-06f);
    p = __fadd_rn(__fmul_rn(p, w), -4.39150654e-06f);
    p = __fadd_rn(__fmul_rn(p, w), 0.00021858087f);
    p = __fadd_rn(__fmul_rn(p, w), -0.00125372503f);
    p = __fadd_rn(__fmul_rn(p, w), -0.00417768164f);
    p = __fadd_rn(__fmul_rn(p, w), 0.246640727f);
    p = __fadd_rn(__fmul_rn(p, w), 1.50140941f);
  } else {
    w = __fsub_rn(sqrtf(w), 3.0f);
    p = -0.000200214257f;
    p = __fadd_rn(__fmul_rn(p, w), 0.000100950558f);
    p = __fadd_rn(__fmul_rn(p, w), 0.00134934322f);
    p = __fadd_rn(__fmul_rn(p, w), -0.00367342844f);
    p = __fadd_rn(__fmul_rn(p, w), 0.00573950773f);
    p = __fadd_rn(__fmul_rn(p, w), -0.0076224613f);
    p = __fadd_rn(__fmul_rn(p, w), 0.00943887047f);
    p = __fadd_rn(__fmul_rn(p, w), 1.00167406f);
    p = __fadd_rn(__fmul_rn(p, w), 2.83297682f);
  }
  return __fmul_rn(p, x);
}

// eps[e] of jax.random.normal under jax_threefry_partitionable=True:
// per-element counter PRF, counter (hi=0, lo=e), draw = x0out ^ x1out.
static __device__ inline float jax_normal_elem(uint32_t k0, uint32_t k1, uint32_t e) {
  uint32_t c0 = 0u, c1 = e;
  tf2x32(k0, k1, c0, c1);
  uint32_t bits = c0 ^ c1;
  float f = __fsub_rn(__uint_as_float((bits >> 9) | 0x3F800000u), 1.0f); // [0,1)
  const float lo = -0.99999994f;
  float u = fmaxf(lo, __fadd_rn(__fmul_rn(f, 2.0f), lo));
  return __fmul_rn(1.41421356237309515f, erfinv_xla(u));
}

static __device__ inline float softplus_(float x) {
  return __fadd_rn(fmaxf(x, 0.0f), log1pf(expf(-fabsf(x))));
}

static __device__ inline float sigmoid_(float x) {
  if (x >= 0.0f) return 1.0f / (1.0f + expf(-x));
  float e = expf(x);
  return e / (1.0f + e);
}

// ---------------- Kernel 1: argmax, shuffle-free, phase-split blocks ----------------
// bid = 2*b + phase. phase 0: col-argmax (axis=1) -> idx_i.  phase 1: row-argmax
// (axis=2) -> idx_p. No LDS, no cross-lane ops; 4 independent compare chains.
__global__ __launch_bounds__(256) void argmax_kernel(
    const float* __restrict__ sim, int* __restrict__ idx_p, int* __restrict__ idx_i) {
  int bid = blockIdx.x;
  int b = bid >> 1, phase = bid & 1;
  int j = threadIdx.x;
  if (j >= SS) return;
  const float* S = sim + (size_t)b * (TT * TT);

  if (phase == 0) {
    // column argmax: thread j scans down column j (coalesced across lanes)
    const float* p = S + TT + 1 + j;   // S[1][1+j]
    float v0 = -INFINITY, v1 = -INFINITY, v2 = -INFINITY, v3 = -INFINITY;
    int t0 = 0, t1 = 1, t2 = 2, t3 = 3;
    for (int t = 0; t < SS; t += 4) {
      float a = p[(size_t)(t + 0) * TT];
      float c1 = p[(size_t)(t + 1) * TT];
      float c2 = p[(size_t)(t + 2) * TT];
      float c3 = p[(size_t)(t + 3) * TT];
      if (a  > v0) { v0 = a;  t0 = t; }
      if (c1 > v1) { v1 = c1; t1 = t + 1; }
      if (c2 > v2) { v2 = c2; t2 = t + 2; }
      if (c3 > v3) { v3 = c3; t3 = t + 3; }
    }
    float bv = v0; int bt = t0;
    if (v1 > bv || (v1 == bv && t1 < bt)) { bv = v1; bt = t1; }
    if (v2 > bv || (v2 == bv && t2 < bt)) { bv = v2; bt = t2; }
    if (v3 > bv || (v3 == bv && t3 < bt)) { bv = v3; bt = t3; }
    idx_i[(size_t)b * SS + j] = bt;
  } else {
    // row argmax: thread j scans row j in 16-wide chunks (full 64B-line use
    // within one iteration -> no cross-iteration L1 reuse needed)
    const float* q = S + (size_t)(j + 1) * TT + 1;   // S[1+j][1]
    float v[4] = {-INFINITY, -INFINITY, -INFINITY, -INFINITY};
    int   ci[4] = {0, 1, 2, 3};
    for (int c = 0; c < 192; c += 16) {
      #pragma unroll
      for (int u = 0; u < 16; ++u) {
        float x = q[c + u];
        int k = u & 3;
        if (x > v[k]) { v[k] = x; ci[k] = c + u; }
      }
    }
    #pragma unroll
    for (int u = 0; u < 4; ++u) {
      float x = q[192 + u];
      if (x > v[u]) { v[u] = x; ci[u] = 192 + u; }
    }
    float bv = v[0]; int bc = ci[0];
    #pragma unroll
    for (int k = 1; k < 4; ++k)
      if (v[k] > bv || (v[k] == bv && ci[k] < bc)) { bv = v[k]; bc = ci[k]; }
    idx_p[(size_t)b * SS + j] = bc;
  }
}

// ---------------- Kernel 2: MLP params for all GG rows of one tensor ----------------
__global__ __launch_bounds__(256) void mlp_kernel(
    const float* __restrict__ X,    // (GG, 64) rows
    const float* __restrict__ W1,   // (64,64)
    const float* __restrict__ b1,   // (64)
    const float* __restrict__ W2,   // (64,4)
    const float* __restrict__ b2,   // (4)
    float4* __restrict__ params) {  // (GG) of (mu0,mu1,sg0,sg1)
  __shared__ float XT[64][128];     // transposed x tile
  __shared__ float W1s[64][64];
  __shared__ float W2s[64][4];
  __shared__ float b1s[64];
  __shared__ float b2s[4];

  int tid = threadIdx.x;
  size_t g0 = (size_t)blockIdx.x * 128;

  {
    const float4* w4 = (const float4*)W1;
    float4* s4 = (float4*)&W1s[0][0];
    #pragma unroll
    for (int i = 0; i < 4; ++i) s4[tid + 256 * i] = w4[tid + 256 * i];
  }
  if (tid < 64) {
    ((float4*)&W2s[0][0])[tid] = ((const float4*)W2)[tid];
    b1s[tid] = b1[tid];
  }
  if (tid < 4) b2s[tid] = b2[tid];

  {
    int r = tid & 127, kh = tid >> 7;
    const float4* src = (const float4*)(X + (g0 + (size_t)r) * 64 + kh * 32);
    #pragma unroll
    for (int q = 0; q < 8; ++q) {
      float4 v = src[q];
      int k0 = kh * 32 + q * 4;
      XT[k0 + 0][r] = v.x; XT[k0 + 1][r] = v.y;
      XT[k0 + 2][r] = v.z; XT[k0 + 3][r] = v.w;
    }
  }
  __syncthreads();

  int tr = tid >> 3, tc = tid & 7;
  int r0 = tr * 4, c0 = tc * 8;

  float acc[4][8];
  #pragma unroll
  for (int i = 0; i < 4; ++i)
    #pragma unroll
    for (int j = 0; j < 8; ++j) acc[i][j] = b1s[c0 + j];

  #pragma unroll 4
  for (int k = 0; k < 64; ++k) {
    float4 xv = *(const float4*)&XT[k][r0];
    float4 wa = *(const float4*)&W1s[k][c0];
    float4 wb = *(const float4*)&W1s[k][c0 + 4];
    float xr[4] = {xv.x, xv.y, xv.z, xv.w};
    float wc[8] = {wa.x, wa.y, wa.z, wa.w, wb.x, wb.y, wb.z, wb.w};
    #pragma unroll
    for (int i = 0; i < 4; ++i)
      #pragma unroll
      for (int j = 0; j < 8; ++j)
        acc[i][j] = fmaf(xr[i], wc[j], acc[i][j]);
  }

  #pragma unroll
  for (int i = 0; i < 4; ++i)
    #pragma unroll
    for (int j = 0; j < 8; ++j) acc[i][j] = fmaxf(acc[i][j], 0.0f);

  float p[4][4] = {{0,0,0,0},{0,0,0,0},{0,0,0,0},{0,0,0,0}};
  #pragma unroll
  for (int j = 0; j < 8; ++j) {
    float4 w2 = *(const float4*)&W2s[c0 + j][0];
    #pragma unroll
    for (int i = 0; i < 4; ++i) {
      p[i][0] = fmaf(acc[i][j], w2.x, p[i][0]);
      p[i][1] = fmaf(acc[i][j], w2.y, p[i][1]);
      p[i][2] = fmaf(acc[i][j], w2.z, p[i][2]);
      p[i][3] = fmaf(acc[i][j], w2.w, p[i][3]);
    }
  }
  #pragma unroll
  for (int off = 1; off < 8; off <<= 1)
    #pragma unroll
    for (int i = 0; i < 4; ++i)
      #pragma unroll
      for (int c = 0; c < 4; ++c)
        p[i][c] += __shfl_xor(p[i][c], off);

  if (tc == 0) {
    #pragma unroll
    for (int i = 0; i < 4; ++i) {
      float m0 = p[i][0] + b2s[0];
      float m1 = p[i][1] + b2s[1];
      float s0 = __fadd_rn(softplus_(p[i][2] + b2s[2]), 1e-07f);
      float s1 = __fadd_rn(softplus_(p[i][3] + b2s[3]), 1e-07f);
      params[g0 + r0 + i] = make_float4(m0, m1, s0, s1);
    }
  }
}

// ---------------- Kernel 3: gather params, sample eps, log-prob diff ----------------
__global__ __launch_bounds__(256) void combine_kernel(
    const int* __restrict__ idx_p, const int* __restrict__ idx_i,
    const float4* __restrict__ params_t, const float4* __restrict__ params_i,
    float* __restrict__ out,
    uint32_t k1a, uint32_t k1b, uint32_t k2a, uint32_t k2b) {
  int id = blockIdx.x * 256 + threadIdx.x;
  int side = (id >= MM) ? 1 : 0;             // wave-uniform (MM % 256 == 0)
  int m = id - side * MM;
  int b = m / SS;
  int t = m - b * SS;

  float4 pa, pb;
  uint32_t ka, kb;
  if (!side) {
    pa = params_t[(size_t)b * TT + 1 + t];
    pb = params_i[(size_t)b * TT + idx_p[m]];
    ka = k1a; kb = k1b;
  } else {
    pa = params_i[(size_t)b * TT + 1 + t];
    pb = params_t[(size_t)b * TT + idx_i[m]];
    ka = k2a; kb = k2b;
  }

  uint32_t e0 = 2u * (uint32_t)m;
  float eps0 = jax_normal_elem(ka, kb, e0);
  float eps1 = jax_normal_elem(ka, kb, e0 + 1u);

  float z0 = __fadd_rn(pa.x, __fmul_rn(pa.z, eps0));
  float z1 = __fadd_rn(pa.y, __fmul_rn(pa.w, eps1));

  const float HLOG2PI = 0.91893853320467274f;
  float ea0 = __fsub_rn(z0, pa.x) / pa.z;
  float ea1 = __fsub_rn(z1, pa.y) / pa.w;
  float eb0 = __fsub_rn(z0, pb.x) / pb.z;
  float eb1 = __fsub_rn(z1, pb.y) / pb.w;

  float la0 = __fsub_rn(__fsub_rn(__fmul_rn(-0.5f, __fmul_rn(ea0, ea0)), logf(pa.z)), HLOG2PI);
  float la1 = __fsub_rn(__fsub_rn(__fmul_rn(-0.5f, __fmul_rn(ea1, ea1)), logf(pa.w)), HLOG2PI);
  float lb0 = __fsub_rn(__fsub_rn(__fmul_rn(-0.5f, __fmul_rn(eb0, eb0)), logf(pb.z)), HLOG2PI);
  float lb1 = __fsub_rn(__fsub_rn(__fmul_rn(-0.5f, __fmul_rn(eb1, eb1)), logf(pb.w)), HLOG2PI);
  float lpa = __fadd_rn(la0, la1);
  float lpb = __fadd_rn(lb0, lb1);

  out[id] = sigmoid_(sigmoid_(__fsub_rn(lpa, lpb)));
}

// ---------------- Launch ----------------
extern "C" void kernel_launch(void* const* d_in, const int* in_sizes, int n_in,
                              void* d_out, int out_size, void* d_ws, size_t ws_size,
                              hipStream_t stream) {
  const float* post  = (const float*)d_in[0];
  const float* image = (const float*)d_in[1];
  const float* sim   = (const float*)d_in[2];
  const float* tW1 = (const float*)d_in[3];
  const float* tb1 = (const float*)d_in[4];
  const float* tW2 = (const float*)d_in[5];
  const float* tb2 = (const float*)d_in[6];
  const float* iW1 = (const float*)d_in[7];
  const float* ib1 = (const float*)d_in[8];
  const float* iW2 = (const float*)d_in[9];
  const float* ib2 = (const float*)d_in[10];
  float* out = (float*)d_out;

  int* idx_p = (int*)d_ws;
  int* idx_i = idx_p + MM;
  float4* params_t = (float4*)(idx_i + MM);       // GG float4s
  float4* params_i = params_t + GG;

  // jax.random.split(key(42)) under threefry_partitionable:
  // child i = full 64-bit PRF output at counter (hi=0, lo=i).
  uint32_t k1a = 0, k1b = 0; tf2x32(0u, 42u, k1a, k1b);   // child 0
  uint32_t k2a = 0, k2b = 1; tf2x32(0u, 42u, k2a, k2b);   // child 1

  argmax_kernel<<<dim3(2 * BB), dim3(256), 0, stream>>>(sim, idx_p, idx_i);
  mlp_kernel<<<dim3(GG / 128), dim3(256), 0, stream>>>(post,  tW1, tb1, tW2, tb2, params_t);
  mlp_kernel<<<dim3(GG / 128), dim3(256), 0, stream>>>(image, iW1, ib1, iW2, ib2, params_i);
  combine_kernel<<<dim3((2 * MM) / 256), dim3(256), 0, stream>>>(
      idx_p, idx_i, params_t, params_i, out, k1a, k1b, k2a, k2b);
}

// Round 6
// 144.874 us; speedup vs baseline: 2.1143x; 1.0392x over previous
//
#include <hip/hip_runtime.h>
#include <stdint.h>
#include <math.h>

// Problem constants
#define BB   1024
#define TT   197
#define SS   196
#define DD   64
#define MM   200704   // BB*SS   (outputs per side)
#define GG   201728   // BB*TT   (param rows per table)
#define MROWS 256     // rows per MLP block
#define MBLK  788     // GG/MROWS blocks per side

// ---------------- Threefry2x32 (exact JAX rolled variant) ----------------
static __host__ __device__ inline uint32_t rotl_(uint32_t x, int r) {
  return (x << r) | (x >> (32 - r));
}

static __host__ __device__ inline void tf2x32(uint32_t k0, uint32_t k1,
                                              uint32_t& x0, uint32_t& x1) {
  uint32_t ks2 = k0 ^ k1 ^ 0x1BD11BDAu;
  x0 += k0; x1 += k1;
  x0 += x1; x1 = rotl_(x1,13); x1 ^= x0;
  x0 += x1; x1 = rotl_(x1,15); x1 ^= x0;
  x0 += x1; x1 = rotl_(x1,26); x1 ^= x0;
  x0 += x1; x1 = rotl_(x1, 6); x1 ^= x0;
  x0 += k1;  x1 += ks2 + 1u;
  x0 += x1; x1 = rotl_(x1,17); x1 ^= x0;
  x0 += x1; x1 = rotl_(x1,29); x1 ^= x0;
  x0 += x1; x1 = rotl_(x1,16); x1 ^= x0;
  x0 += x1; x1 = rotl_(x1,24); x1 ^= x0;
  x0 += ks2; x1 += k0 + 2u;
  x0 += x1; x1 = rotl_(x1,13); x1 ^= x0;
  x0 += x1; x1 = rotl_(x1,15); x1 ^= x0;
  x0 += x1; x1 = rotl_(x1,26); x1 ^= x0;
  x0 += x1; x1 = rotl_(x1, 6); x1 ^= x0;
  x0 += k0;  x1 += k1 + 3u;
  x0 += x1; x1 = rotl_(x1,17); x1 ^= x0;
  x0 += x1; x1 = rotl_(x1,29); x1 ^= x0;
  x0 += x1; x1 = rotl_(x1,16); x1 ^= x0;
  x0 += x1; x1 = rotl_(x1,24); x1 ^= x0;
  x0 += k1;  x1 += ks2 + 4u;
  x0 += x1; x1 = rotl_(x1,13); x1 ^= x0;
  x0 += x1; x1 = rotl_(x1,15); x1 ^= x0;
  x0 += x1; x1 = rotl_(x1,26); x1 ^= x0;
  x0 += x1; x1 = rotl_(x1, 6); x1 ^= x0;
  x0 += ks2; x1 += k0 + 5u;
}

// XLA ErfInv (float32 Giles polynomial), exact non-contracted rounding.
static __device__ inline float erfinv_xla(float x) {
  float w = -log1pf(-__fmul_rn(x, x));
  float p;
  if (w < 5.0f) {
    w = __fsub_rn(w, 2.5f);
    p = 2.81022636e-08f;
    p = __fadd_rn(__fmul_rn(p, w), 3.43273939e-07f);
    p = __fadd_rn(__fmul_rn(p, w), -3.5233877e-06f);
    p = __fadd_rn(__fmul_rn(p, w), -4.39150654e-06f);
    p = __fadd_rn(__fmul_rn(p, w), 0.00021858087f);
    p = __fadd_rn(__fmul_rn(p, w), -0.00125372503f);
    p = __fadd_rn(__fmul_rn(p, w), -0.00417768164f);
    p = __fadd_rn(__fmul_rn(p, w), 0.246640727f);
    p = __fadd_rn(__fmul_rn(p, w), 1.50140941f);
  } else {
    w = __fsub_rn(sqrtf(w), 3.0f);
    p = -0.000200214257f;
    p = __fadd_rn(__fmul_rn(p, w), 0.000100950558f);
    p = __fadd_rn(__fmul_rn(p, w), 0.00134934322f);
    p = __fadd_rn(__fmul_rn(p, w), -0.00367342844f);
    p = __fadd_rn(__fmul_rn(p, w), 0.00573950773f);
    p = __fadd_rn(__fmul_rn(p, w), -0.0076224613f);
    p = __fadd_rn(__fmul_rn(p, w), 0.00943887047f);
    p = __fadd_rn(__fmul_rn(p, w), 1.00167406f);
    p = __fadd_rn(__fmul_rn(p, w), 2.83297682f);
  }
  return __fmul_rn(p, x);
}

// eps[e] of jax.random.normal under jax_threefry_partitionable=True:
// per-element counter PRF, counter (hi=0, lo=e), draw = x0out ^ x1out.
static __device__ inline float jax_normal_elem(uint32_t k0, uint32_t k1, uint32_t e) {
  uint32_t c0 = 0u, c1 = e;
  tf2x32(k0, k1, c0, c1);
  uint32_t bits = c0 ^ c1;
  float f = __fsub_rn(__uint_as_float((bits >> 9) | 0x3F800000u), 1.0f); // [0,1)
  const float lo = -0.99999994f;
  float u = fmaxf(lo, __fadd_rn(__fmul_rn(f, 2.0f), lo));
  return __fmul_rn(1.41421356237309515f, erfinv_xla(u));
}

static __device__ inline float softplus_(float x) {
  return __fadd_rn(fmaxf(x, 0.0f), log1pf(expf(-fabsf(x))));
}

static __device__ inline float sigmoid_(float x) {
  if (x >= 0.0f) return 1.0f / (1.0f + expf(-x));
  float e = expf(x);
  return e / (1.0f + e);
}

// ---------------- Kernel 1: argmax, shuffle-free, phase-split blocks ----------------
// (unchanged from round 5)
__global__ __launch_bounds__(256) void argmax_kernel(
    const float* __restrict__ sim, int* __restrict__ idx_p, int* __restrict__ idx_i) {
  int bid = blockIdx.x;
  int b = bid >> 1, phase = bid & 1;
  int j = threadIdx.x;
  if (j >= SS) return;
  const float* S = sim + (size_t)b * (TT * TT);

  if (phase == 0) {
    const float* p = S + TT + 1 + j;   // S[1][1+j]
    float v0 = -INFINITY, v1 = -INFINITY, v2 = -INFINITY, v3 = -INFINITY;
    int t0 = 0, t1 = 1, t2 = 2, t3 = 3;
    for (int t = 0; t < SS; t += 4) {
      float a = p[(size_t)(t + 0) * TT];
      float c1 = p[(size_t)(t + 1) * TT];
      float c2 = p[(size_t)(t + 2) * TT];
      float c3 = p[(size_t)(t + 3) * TT];
      if (a  > v0) { v0 = a;  t0 = t; }
      if (c1 > v1) { v1 = c1; t1 = t + 1; }
      if (c2 > v2) { v2 = c2; t2 = t + 2; }
      if (c3 > v3) { v3 = c3; t3 = t + 3; }
    }
    float bv = v0; int bt = t0;
    if (v1 > bv || (v1 == bv && t1 < bt)) { bv = v1; bt = t1; }
    if (v2 > bv || (v2 == bv && t2 < bt)) { bv = v2; bt = t2; }
    if (v3 > bv || (v3 == bv && t3 < bt)) { bv = v3; bt = t3; }
    idx_i[(size_t)b * SS + j] = bt;
  } else {
    const float* q = S + (size_t)(j + 1) * TT + 1;   // S[1+j][1]
    float v[4] = {-INFINITY, -INFINITY, -INFINITY, -INFINITY};
    int   ci[4] = {0, 1, 2, 3};
    for (int c = 0; c < 192; c += 16) {
      #pragma unroll
      for (int u = 0; u < 16; ++u) {
        float x = q[c + u];
        int k = u & 3;
        if (x > v[k]) { v[k] = x; ci[k] = c + u; }
      }
    }
    #pragma unroll
    for (int u = 0; u < 4; ++u) {
      float x = q[192 + u];
      if (x > v[u]) { v[u] = x; ci[u] = 192 + u; }
    }
    float bv = v[0]; int bc = ci[0];
    #pragma unroll
    for (int k = 1; k < 4; ++k)
      if (v[k] > bv || (v[k] == bv && ci[k] < bc)) { bv = v[k]; bc = ci[k]; }
    idx_p[(size_t)b * SS + j] = bc;
  }
}

// ---------------- Kernel 2: MLP, both sides, 8x8 per-thread tile ----------------
// 256 rows/block, 256 threads: thread (tr,tc) computes rows r0..r0+7 x cols
// c0..c0+7. K split into two 32-deep phases staged in XT[32][256] (transposed).
// DS per k-step: 4x ds_read_b128 (64B) feeding 64 FMA -> 1.0 B/FMA.
__global__ __launch_bounds__(256) void mlp_kernel(
    const float* __restrict__ Xp, const float* __restrict__ Xi,
    const float* __restrict__ tW1, const float* __restrict__ tb1,
    const float* __restrict__ tW2, const float* __restrict__ tb2,
    const float* __restrict__ iW1, const float* __restrict__ ib1,
    const float* __restrict__ iW2, const float* __restrict__ ib2,
    float4* __restrict__ params_t, float4* __restrict__ params_i) {
  __shared__ float XT[32][MROWS];   // transposed x, one 32-k phase
  __shared__ float W1s[64][64];
  __shared__ float W2s[64][4];
  __shared__ float b1s[64];
  __shared__ float b2s[4];

  int tid = threadIdx.x;
  int bid = blockIdx.x;
  int side = (bid >= MBLK) ? 1 : 0;
  const float* X  = side ? Xi  : Xp;
  const float* W1 = side ? iW1 : tW1;
  const float* B1 = side ? ib1 : tb1;
  const float* W2 = side ? iW2 : tW2;
  const float* B2 = side ? ib2 : tb2;
  float4* params  = side ? params_i : params_t;
  size_t g0 = (size_t)(side ? bid - MBLK : bid) * MROWS;

  // stage weights (conflict-light: 2 lanes/bank or broadcast)
  {
    const float4* w4 = (const float4*)W1;
    float4* s4 = (float4*)&W1s[0][0];
    #pragma unroll
    for (int i = 0; i < 4; ++i) s4[tid + 256 * i] = w4[tid + 256 * i];
  }
  if (tid < 64) {
    ((float4*)&W2s[0][0])[tid] = ((const float4*)W2)[tid];
    b1s[tid] = B1[tid];
  }
  if (tid < 4) b2s[tid] = B2[tid];

  const float* xrow = X + (g0 + (size_t)tid) * 64;
  int tr = tid >> 3, tc = tid & 7;
  int r0 = tr * 8, c0 = tc * 8;

  // ---- phase 0 stage: thread owns row tid, k = 0..31 ----
  {
    const float4* src = (const float4*)(xrow);
    #pragma unroll
    for (int q = 0; q < 8; ++q) {
      float4 v = src[q];
      XT[q * 4 + 0][tid] = v.x; XT[q * 4 + 1][tid] = v.y;
      XT[q * 4 + 2][tid] = v.z; XT[q * 4 + 3][tid] = v.w;
    }
  }
  __syncthreads();

  float acc[8][8];
  #pragma unroll
  for (int i = 0; i < 8; ++i)
    #pragma unroll
    for (int j = 0; j < 8; ++j) acc[i][j] = b1s[c0 + j];

  #pragma unroll 4
  for (int k = 0; k < 32; ++k) {
    float4 xa = *(const float4*)&XT[k][r0];
    float4 xb = *(const float4*)&XT[k][r0 + 4];
    float4 wa = *(const float4*)&W1s[k][c0];
    float4 wb = *(const float4*)&W1s[k][c0 + 4];
    float xr[8] = {xa.x, xa.y, xa.z, xa.w, xb.x, xb.y, xb.z, xb.w};
    float wc[8] = {wa.x, wa.y, wa.z, wa.w, wb.x, wb.y, wb.z, wb.w};
    #pragma unroll
    for (int i = 0; i < 8; ++i)
      #pragma unroll
      for (int j = 0; j < 8; ++j)
        acc[i][j] = fmaf(xr[i], wc[j], acc[i][j]);
  }

  // ---- phase 1 stage: k = 32..63 ----
  __syncthreads();
  {
    const float4* src = (const float4*)(xrow + 32);
    #pragma unroll
    for (int q = 0; q < 8; ++q) {
      float4 v = src[q];
      XT[q * 4 + 0][tid] = v.x; XT[q * 4 + 1][tid] = v.y;
      XT[q * 4 + 2][tid] = v.z; XT[q * 4 + 3][tid] = v.w;
    }
  }
  __syncthreads();

  #pragma unroll 4
  for (int k = 0; k < 32; ++k) {
    float4 xa = *(const float4*)&XT[k][r0];
    float4 xb = *(const float4*)&XT[k][r0 + 4];
    float4 wa = *(const float4*)&W1s[32 + k][c0];
    float4 wb = *(const float4*)&W1s[32 + k][c0 + 4];
    float xr[8] = {xa.x, xa.y, xa.z, xa.w, xb.x, xb.y, xb.z, xb.w};
    float wc[8] = {wa.x, wa.y, wa.z, wa.w, wb.x, wb.y, wb.z, wb.w};
    #pragma unroll
    for (int i = 0; i < 8; ++i)
      #pragma unroll
      for (int j = 0; j < 8; ++j)
        acc[i][j] = fmaf(xr[i], wc[j], acc[i][j]);
  }

  // relu
  #pragma unroll
  for (int i = 0; i < 8; ++i)
    #pragma unroll
    for (int j = 0; j < 8; ++j) acc[i][j] = fmaxf(acc[i][j], 0.0f);

  // second matmul: partial over this thread's 8 j's, reduce across 8 tc lanes
  float p[8][4];
  #pragma unroll
  for (int i = 0; i < 8; ++i)
    #pragma unroll
    for (int c = 0; c < 4; ++c) p[i][c] = 0.0f;
  #pragma unroll
  for (int j = 0; j < 8; ++j) {
    float4 w2 = *(const float4*)&W2s[c0 + j][0];
    #pragma unroll
    for (int i = 0; i < 8; ++i) {
      p[i][0] = fmaf(acc[i][j], w2.x, p[i][0]);
      p[i][1] = fmaf(acc[i][j], w2.y, p[i][1]);
      p[i][2] = fmaf(acc[i][j], w2.z, p[i][2]);
      p[i][3] = fmaf(acc[i][j], w2.w, p[i][3]);
    }
  }
  #pragma unroll
  for (int off = 1; off < 8; off <<= 1)
    #pragma unroll
    for (int i = 0; i < 8; ++i)
      #pragma unroll
      for (int c = 0; c < 4; ++c)
        p[i][c] += __shfl_xor(p[i][c], off);

  if (tc == 0) {
    #pragma unroll
    for (int i = 0; i < 8; ++i) {
      float m0 = p[i][0] + b2s[0];
      float m1 = p[i][1] + b2s[1];
      float s0 = __fadd_rn(softplus_(p[i][2] + b2s[2]), 1e-07f);
      float s1 = __fadd_rn(softplus_(p[i][3] + b2s[3]), 1e-07f);
      params[g0 + r0 + i] = make_float4(m0, m1, s0, s1);
    }
  }
}

// ---------------- Kernel 3: gather params, sample eps, log-prob diff ----------------
__global__ __launch_bounds__(256) void combine_kernel(
    const int* __restrict__ idx_p, const int* __restrict__ idx_i,
    const float4* __restrict__ params_t, const float4* __restrict__ params_i,
    float* __restrict__ out,
    uint32_t k1a, uint32_t k1b, uint32_t k2a, uint32_t k2b) {
  int id = blockIdx.x * 256 + threadIdx.x;
  int side = (id >= MM) ? 1 : 0;             // wave-uniform (MM % 256 == 0)
  int m = id - side * MM;
  int b = m / SS;
  int t = m - b * SS;

  float4 pa, pb;
  uint32_t ka, kb;
  if (!side) {
    pa = params_t[(size_t)b * TT + 1 + t];
    pb = params_i[(size_t)b * TT + idx_p[m]];
    ka = k1a; kb = k1b;
  } else {
    pa = params_i[(size_t)b * TT + 1 + t];
    pb = params_t[(size_t)b * TT + idx_i[m]];
    ka = k2a; kb = k2b;
  }

  uint32_t e0 = 2u * (uint32_t)m;
  float eps0 = jax_normal_elem(ka, kb, e0);
  float eps1 = jax_normal_elem(ka, kb, e0 + 1u);

  float z0 = __fadd_rn(pa.x, __fmul_rn(pa.z, eps0));
  float z1 = __fadd_rn(pa.y, __fmul_rn(pa.w, eps1));

  const float HLOG2PI = 0.91893853320467274f;
  float ea0 = __fsub_rn(z0, pa.x) / pa.z;
  float ea1 = __fsub_rn(z1, pa.y) / pa.w;
  float eb0 = __fsub_rn(z0, pb.x) / pb.z;
  float eb1 = __fsub_rn(z1, pb.y) / pb.w;

  float la0 = __fsub_rn(__fsub_rn(__fmul_rn(-0.5f, __fmul_rn(ea0, ea0)), logf(pa.z)), HLOG2PI);
  float la1 = __fsub_rn(__fsub_rn(__fmul_rn(-0.5f, __fmul_rn(ea1, ea1)), logf(pa.w)), HLOG2PI);
  float lb0 = __fsub_rn(__fsub_rn(__fmul_rn(-0.5f, __fmul_rn(eb0, eb0)), logf(pb.z)), HLOG2PI);
  float lb1 = __fsub_rn(__fsub_rn(__fmul_rn(-0.5f, __fmul_rn(eb1, eb1)), logf(pb.w)), HLOG2PI);
  float lpa = __fadd_rn(la0, la1);
  float lpb = __fadd_rn(lb0, lb1);

  out[id] = sigmoid_(sigmoid_(__fsub_rn(lpa, lpb)));
}

// ---------------- Launch ----------------
extern "C" void kernel_launch(void* const* d_in, const int* in_sizes, int n_in,
                              void* d_out, int out_size, void* d_ws, size_t ws_size,
                              hipStream_t stream) {
  const float* post  = (const float*)d_in[0];
  const float* image = (const float*)d_in[1];
  const float* sim   = (const float*)d_in[2];
  const float* tW1 = (const float*)d_in[3];
  const float* tb1 = (const float*)d_in[4];
  const float* tW2 = (const float*)d_in[5];
  const float* tb2 = (const float*)d_in[6];
  const float* iW1 = (const float*)d_in[7];
  const float* ib1 = (const float*)d_in[8];
  const float* iW2 = (const float*)d_in[9];
  const float* ib2 = (const float*)d_in[10];
  float* out = (float*)d_out;

  int* idx_p = (int*)d_ws;
  int* idx_i = idx_p + MM;
  float4* params_t = (float4*)(idx_i + MM);       // GG float4s
  float4* params_i = params_t + GG;

  // jax.random.split(key(42)) under threefry_partitionable:
  // child i = full 64-bit PRF output at counter (hi=0, lo=i).
  uint32_t k1a = 0, k1b = 0; tf2x32(0u, 42u, k1a, k1b);   // child 0
  uint32_t k2a = 0, k2b = 1; tf2x32(0u, 42u, k2a, k2b);   // child 1

  argmax_kernel<<<dim3(2 * BB), dim3(256), 0, stream>>>(sim, idx_p, idx_i);
  mlp_kernel<<<dim3(2 * MBLK), dim3(256), 0, stream>>>(
      post, image, tW1, tb1, tW2, tb2, iW1, ib1, iW2, ib2, params_t, params_i);
  combine_kernel<<<dim3((2 * MM) / 256), dim3(256), 0, stream>>>(
      idx_p, idx_i, params_t, params_i, out, k1a, k1b, k2a, k2b);
}

// Round 7
// 136.658 us; speedup vs baseline: 2.2414x; 1.0601x over previous
//
#include <hip/hip_runtime.h>
#include <stdint.h>
#include <math.h>

// Problem constants
#define BB   1024
#define TT   197
#define SS   196
#define DD   64
#define MM   200704   // BB*SS   (outputs per side)
#define GG   201728   // BB*TT   (param rows per table)
#define MROWS 256     // rows per MLP block
#define MBLK  788     // GG/MROWS blocks per side

// ---------------- Threefry2x32 (exact JAX rolled variant) ----------------
static __host__ __device__ inline uint32_t rotl_(uint32_t x, int r) {
  return (x << r) | (x >> (32 - r));
}

static __host__ __device__ inline void tf2x32(uint32_t k0, uint32_t k1,
                                              uint32_t& x0, uint32_t& x1) {
  uint32_t ks2 = k0 ^ k1 ^ 0x1BD11BDAu;
  x0 += k0; x1 += k1;
  x0 += x1; x1 = rotl_(x1,13); x1 ^= x0;
  x0 += x1; x1 = rotl_(x1,15); x1 ^= x0;
  x0 += x1; x1 = rotl_(x1,26); x1 ^= x0;
  x0 += x1; x1 = rotl_(x1, 6); x1 ^= x0;
  x0 += k1;  x1 += ks2 + 1u;
  x0 += x1; x1 = rotl_(x1,17); x1 ^= x0;
  x0 += x1; x1 = rotl_(x1,29); x1 ^= x0;
  x0 += x1; x1 = rotl_(x1,16); x1 ^= x0;
  x0 += x1; x1 = rotl_(x1,24); x1 ^= x0;
  x0 += ks2; x1 += k0 + 2u;
  x0 += x1; x1 = rotl_(x1,13); x1 ^= x0;
  x0 += x1; x1 = rotl_(x1,15); x1 ^= x0;
  x0 += x1; x1 = rotl_(x1,26); x1 ^= x0;
  x0 += x1; x1 = rotl_(x1, 6); x1 ^= x0;
  x0 += k0;  x1 += k1 + 3u;
  x0 += x1; x1 = rotl_(x1,17); x1 ^= x0;
  x0 += x1; x1 = rotl_(x1,29); x1 ^= x0;
  x0 += x1; x1 = rotl_(x1,16); x1 ^= x0;
  x0 += x1; x1 = rotl_(x1,24); x1 ^= x0;
  x0 += k1;  x1 += ks2 + 4u;
  x0 += x1; x1 = rotl_(x1,13); x1 ^= x0;
  x0 += x1; x1 = rotl_(x1,15); x1 ^= x0;
  x0 += x1; x1 = rotl_(x1,26); x1 ^= x0;
  x0 += x1; x1 = rotl_(x1, 6); x1 ^= x0;
  x0 += ks2; x1 += k0 + 5u;
}

// XLA ErfInv (float32 Giles polynomial), exact non-contracted rounding.
static __device__ inline float erfinv_xla(float x) {
  float w = -log1pf(-__fmul_rn(x, x));
  float p;
  if (w < 5.0f) {
    w = __fsub_rn(w, 2.5f);
    p = 2.81022636e-08f;
    p = __fadd_rn(__fmul_rn(p, w), 3.43273939e-07f);
    p = __fadd_rn(__fmul_rn(p, w), -3.5233877e-06f);
    p = __fadd_rn(__fmul_rn(p, w), -4.39150654e-06f);
    p = __fadd_rn(__fmul_rn(p, w), 0.00021858087f);
    p = __fadd_rn(__fmul_rn(p, w), -0.00125372503f);
    p = __fadd_rn(__fmul_rn(p, w), -0.00417768164f);
    p = __fadd_rn(__fmul_rn(p, w), 0.246640727f);
    p = __fadd_rn(__fmul_rn(p, w), 1.50140941f);
  } else {
    w = __fsub_rn(sqrtf(w), 3.0f);
    p = -0.000200214257f;
    p = __fadd_rn(__fmul_rn(p, w), 0.000100950558f);
    p = __fadd_rn(__fmul_rn(p, w), 0.00134934322f);
    p = __fadd_rn(__fmul_rn(p, w), -0.00367342844f);
    p = __fadd_rn(__fmul_rn(p, w), 0.00573950773f);
    p = __fadd_rn(__fmul_rn(p, w), -0.0076224613f);
    p = __fadd_rn(__fmul_rn(p, w), 0.00943887047f);
    p = __fadd_rn(__fmul_rn(p, w), 1.00167406f);
    p = __fadd_rn(__fmul_rn(p, w), 2.83297682f);
  }
  return __fmul_rn(p, x);
}

// eps[e] of jax.random.normal under jax_threefry_partitionable=True:
// per-element counter PRF, counter (hi=0, lo=e), draw = x0out ^ x1out.
static __device__ inline float jax_normal_elem(uint32_t k0, uint32_t k1, uint32_t e) {
  uint32_t c0 = 0u, c1 = e;
  tf2x32(k0, k1, c0, c1);
  uint32_t bits = c0 ^ c1;
  float f = __fsub_rn(__uint_as_float((bits >> 9) | 0x3F800000u), 1.0f); // [0,1)
  const float lo = -0.99999994f;
  float u = fmaxf(lo, __fadd_rn(__fmul_rn(f, 2.0f), lo));
  return __fmul_rn(1.41421356237309515f, erfinv_xla(u));
}

static __device__ inline float softplus_(float x) {
  return __fadd_rn(fmaxf(x, 0.0f), log1pf(expf(-fabsf(x))));
}

static __device__ inline float sigmoid_(float x) {
  if (x >= 0.0f) return 1.0f / (1.0f + expf(-x));
  float e = expf(x);
  return e / (1.0f + e);
}

// ---------------- Kernel 1: argmax, shuffle-free, phase-split blocks ----------------
// (unchanged)
__global__ __launch_bounds__(256) void argmax_kernel(
    const float* __restrict__ sim, int* __restrict__ idx_p, int* __restrict__ idx_i) {
  int bid = blockIdx.x;
  int b = bid >> 1, phase = bid & 1;
  int j = threadIdx.x;
  if (j >= SS) return;
  const float* S = sim + (size_t)b * (TT * TT);

  if (phase == 0) {
    const float* p = S + TT + 1 + j;   // S[1][1+j]
    float v0 = -INFINITY, v1 = -INFINITY, v2 = -INFINITY, v3 = -INFINITY;
    int t0 = 0, t1 = 1, t2 = 2, t3 = 3;
    for (int t = 0; t < SS; t += 4) {
      float a = p[(size_t)(t + 0) * TT];
      float c1 = p[(size_t)(t + 1) * TT];
      float c2 = p[(size_t)(t + 2) * TT];
      float c3 = p[(size_t)(t + 3) * TT];
      if (a  > v0) { v0 = a;  t0 = t; }
      if (c1 > v1) { v1 = c1; t1 = t + 1; }
      if (c2 > v2) { v2 = c2; t2 = t + 2; }
      if (c3 > v3) { v3 = c3; t3 = t + 3; }
    }
    float bv = v0; int bt = t0;
    if (v1 > bv || (v1 == bv && t1 < bt)) { bv = v1; bt = t1; }
    if (v2 > bv || (v2 == bv && t2 < bt)) { bv = v2; bt = t2; }
    if (v3 > bv || (v3 == bv && t3 < bt)) { bv = v3; bt = t3; }
    idx_i[(size_t)b * SS + j] = bt;
  } else {
    const float* q = S + (size_t)(j + 1) * TT + 1;   // S[1+j][1]
    float v[4] = {-INFINITY, -INFINITY, -INFINITY, -INFINITY};
    int   ci[4] = {0, 1, 2, 3};
    for (int c = 0; c < 192; c += 16) {
      #pragma unroll
      for (int u = 0; u < 16; ++u) {
        float x = q[c + u];
        int k = u & 3;
        if (x > v[k]) { v[k] = x; ci[k] = c + u; }
      }
    }
    #pragma unroll
    for (int u = 0; u < 4; ++u) {
      float x = q[192 + u];
      if (x > v[u]) { v[u] = x; ci[u] = 192 + u; }
    }
    float bv = v[0]; int bc = ci[0];
    #pragma unroll
    for (int k = 1; k < 4; ++k)
      if (v[k] > bv || (v[k] == bv && ci[k] < bc)) { bv = v[k]; bc = ci[k]; }
    idx_p[(size_t)b * SS + j] = bc;
  }
}

// ---------------- Kernel 2: MLP, both sides, 8x8 tile, 4x16-k phases ----------------
// LDS = XT 16KB + W1s 16KB + small = 34.1 KB -> 4 blocks/CU (16 waves).
// Next-phase X prefetched into registers before each barrier; ds_write after.
// FMA k-order identical to previous round -> bitwise-identical params.
__global__ __launch_bounds__(256) void mlp_kernel(
    const float* __restrict__ Xp, const float* __restrict__ Xi,
    const float* __restrict__ tW1, const float* __restrict__ tb1,
    const float* __restrict__ tW2, const float* __restrict__ tb2,
    const float* __restrict__ iW1, const float* __restrict__ ib1,
    const float* __restrict__ iW2, const float* __restrict__ ib2,
    float4* __restrict__ params_t, float4* __restrict__ params_i) {
  __shared__ float XT[16][MROWS];   // transposed x, one 16-k phase
  __shared__ float W1s[64][64];
  __shared__ float W2s[64][4];
  __shared__ float b1s[64];
  __shared__ float b2s[4];

  int tid = threadIdx.x;
  int bid = blockIdx.x;
  int side = (bid >= MBLK) ? 1 : 0;
  const float* X  = side ? Xi  : Xp;
  const float* W1 = side ? iW1 : tW1;
  const float* B1 = side ? ib1 : tb1;
  const float* W2 = side ? iW2 : tW2;
  const float* B2 = side ? ib2 : tb2;
  float4* params  = side ? params_i : params_t;
  size_t g0 = (size_t)(side ? bid - MBLK : bid) * MROWS;

  // stage weights
  {
    const float4* w4 = (const float4*)W1;
    float4* s4 = (float4*)&W1s[0][0];
    #pragma unroll
    for (int i = 0; i < 4; ++i) s4[tid + 256 * i] = w4[tid + 256 * i];
  }
  if (tid < 64) {
    ((float4*)&W2s[0][0])[tid] = ((const float4*)W2)[tid];
    b1s[tid] = B1[tid];
  }
  if (tid < 4) b2s[tid] = B2[tid];

  const float4* xrow4 = (const float4*)(X + (g0 + (size_t)tid) * 64);
  int tr = tid >> 3, tc = tid & 7;
  int r0 = tr * 8, c0 = tc * 8;

  float acc[8][8];
  #pragma unroll
  for (int i = 0; i < 8; ++i)
    #pragma unroll
    for (int j = 0; j < 8; ++j) acc[i][j] = b1s[c0 + j];   // b1s read pre-barrier is
  // WRONG if not staged yet -- b1s is written by tid<64 above with no barrier.
  // Redo safely below after first barrier (overwrite acc there).

  // prefetch phase 0 (k = 0..15)
  float4 pre0 = xrow4[0], pre1 = xrow4[1], pre2 = xrow4[2], pre3 = xrow4[3];

  #pragma unroll
  for (int ph = 0; ph < 4; ++ph) {
    // write current phase to XT
    {
      float4 v;
      v = pre0; XT[ 0][tid] = v.x; XT[ 1][tid] = v.y; XT[ 2][tid] = v.z; XT[ 3][tid] = v.w;
      v = pre1; XT[ 4][tid] = v.x; XT[ 5][tid] = v.y; XT[ 6][tid] = v.z; XT[ 7][tid] = v.w;
      v = pre2; XT[ 8][tid] = v.x; XT[ 9][tid] = v.y; XT[10][tid] = v.z; XT[11][tid] = v.w;
      v = pre3; XT[12][tid] = v.x; XT[13][tid] = v.y; XT[14][tid] = v.z; XT[15][tid] = v.w;
    }
    // issue prefetch of next phase (lands during compute)
    if (ph < 3) {
      pre0 = xrow4[4 * (ph + 1) + 0];
      pre1 = xrow4[4 * (ph + 1) + 1];
      pre2 = xrow4[4 * (ph + 1) + 2];
      pre3 = xrow4[4 * (ph + 1) + 3];
    }
    __syncthreads();

    if (ph == 0) {
      // (re)initialize acc from staged b1s -- now safe after barrier
      #pragma unroll
      for (int i = 0; i < 8; ++i)
        #pragma unroll
        for (int j = 0; j < 8; ++j) acc[i][j] = b1s[c0 + j];
    }

    #pragma unroll
    for (int k = 0; k < 16; ++k) {
      float4 xa = *(const float4*)&XT[k][r0];
      float4 xb = *(const float4*)&XT[k][r0 + 4];
      float4 wa = *(const float4*)&W1s[16 * ph + k][c0];
      float4 wb = *(const float4*)&W1s[16 * ph + k][c0 + 4];
      float xr[8] = {xa.x, xa.y, xa.z, xa.w, xb.x, xb.y, xb.z, xb.w};
      float wc[8] = {wa.x, wa.y, wa.z, wa.w, wb.x, wb.y, wb.z, wb.w};
      #pragma unroll
      for (int i = 0; i < 8; ++i)
        #pragma unroll
        for (int j = 0; j < 8; ++j)
          acc[i][j] = fmaf(xr[i], wc[j], acc[i][j]);
    }
    __syncthreads();   // XT consumed; safe to overwrite next phase
  }

  // relu
  #pragma unroll
  for (int i = 0; i < 8; ++i)
    #pragma unroll
    for (int j = 0; j < 8; ++j) acc[i][j] = fmaxf(acc[i][j], 0.0f);

  // second matmul: partial over this thread's 8 j's, reduce across 8 tc lanes
  float p[8][4];
  #pragma unroll
  for (int i = 0; i < 8; ++i)
    #pragma unroll
    for (int c = 0; c < 4; ++c) p[i][c] = 0.0f;
  #pragma unroll
  for (int j = 0; j < 8; ++j) {
    float4 w2 = *(const float4*)&W2s[c0 + j][0];
    #pragma unroll
    for (int i = 0; i < 8; ++i) {
      p[i][0] = fmaf(acc[i][j], w2.x, p[i][0]);
      p[i][1] = fmaf(acc[i][j], w2.y, p[i][1]);
      p[i][2] = fmaf(acc[i][j], w2.z, p[i][2]);
      p[i][3] = fmaf(acc[i][j], w2.w, p[i][3]);
    }
  }
  #pragma unroll
  for (int off = 1; off < 8; off <<= 1)
    #pragma unroll
    for (int i = 0; i < 8; ++i)
      #pragma unroll
      for (int c = 0; c < 4; ++c)
        p[i][c] += __shfl_xor(p[i][c], off);

  if (tc == 0) {
    #pragma unroll
    for (int i = 0; i < 8; ++i) {
      float m0 = p[i][0] + b2s[0];
      float m1 = p[i][1] + b2s[1];
      float s0 = __fadd_rn(softplus_(p[i][2] + b2s[2]), 1e-07f);
      float s1 = __fadd_rn(softplus_(p[i][3] + b2s[3]), 1e-07f);
      params[g0 + r0 + i] = make_float4(m0, m1, s0, s1);
    }
  }
}

// ---------------- Kernel 3: gather params, sample eps, log-prob diff ----------------
__global__ __launch_bounds__(256) void combine_kernel(
    const int* __restrict__ idx_p, const int* __restrict__ idx_i,
    const float4* __restrict__ params_t, const float4* __restrict__ params_i,
    float* __restrict__ out,
    uint32_t k1a, uint32_t k1b, uint32_t k2a, uint32_t k2b) {
  int id = blockIdx.x * 256 + threadIdx.x;
  int side = (id >= MM) ? 1 : 0;             // wave-uniform (MM % 256 == 0)
  int m = id - side * MM;
  int b = m / SS;
  int t = m - b * SS;

  float4 pa, pb;
  uint32_t ka, kb;
  if (!side) {
    pa = params_t[(size_t)b * TT + 1 + t];
    pb = params_i[(size_t)b * TT + idx_p[m]];
    ka = k1a; kb = k1b;
  } else {
    pa = params_i[(size_t)b * TT + 1 + t];
    pb = params_t[(size_t)b * TT + idx_i[m]];
    ka = k2a; kb = k2b;
  }

  uint32_t e0 = 2u * (uint32_t)m;
  float eps0 = jax_normal_elem(ka, kb, e0);
  float eps1 = jax_normal_elem(ka, kb, e0 + 1u);

  float z0 = __fadd_rn(pa.x, __fmul_rn(pa.z, eps0));
  float z1 = __fadd_rn(pa.y, __fmul_rn(pa.w, eps1));

  const float HLOG2PI = 0.91893853320467274f;
  float ea0 = __fsub_rn(z0, pa.x) / pa.z;
  float ea1 = __fsub_rn(z1, pa.y) / pa.w;
  float eb0 = __fsub_rn(z0, pb.x) / pb.z;
  float eb1 = __fsub_rn(z1, pb.y) / pb.w;

  float la0 = __fsub_rn(__fsub_rn(__fmul_rn(-0.5f, __fmul_rn(ea0, ea0)), logf(pa.z)), HLOG2PI);
  float la1 = __fsub_rn(__fsub_rn(__fmul_rn(-0.5f, __fmul_rn(ea1, ea1)), logf(pa.w)), HLOG2PI);
  float lb0 = __fsub_rn(__fsub_rn(__fmul_rn(-0.5f, __fmul_rn(eb0, eb0)), logf(pb.z)), HLOG2PI);
  float lb1 = __fsub_rn(__fsub_rn(__fmul_rn(-0.5f, __fmul_rn(eb1, eb1)), logf(pb.w)), HLOG2PI);
  float lpa = __fadd_rn(la0, la1);
  float lpb = __fadd_rn(lb0, lb1);

  out[id] = sigmoid_(sigmoid_(__fsub_rn(lpa, lpb)));
}

// ---------------- Launch ----------------
extern "C" void kernel_launch(void* const* d_in, const int* in_sizes, int n_in,
                              void* d_out, int out_size, void* d_ws, size_t ws_size,
                              hipStream_t stream) {
  const float* post  = (const float*)d_in[0];
  const float* image = (const float*)d_in[1];
  const float* sim   = (const float*)d_in[2];
  const float* tW1 = (const float*)d_in[3];
  const float* tb1 = (const float*)d_in[4];
  const float* tW2 = (const float*)d_in[5];
  const float* tb2 = (const float*)d_in[6];
  const float* iW1 = (const float*)d_in[7];
  const float* ib1 = (const float*)d_in[8];
  const float* iW2 = (const float*)d_in[9];
  const float* ib2 = (const float*)d_in[10];
  float* out = (float*)d_out;

  int* idx_p = (int*)d_ws;
  int* idx_i = idx_p + MM;
  float4* params_t = (float4*)(idx_i + MM);       // GG float4s
  float4* params_i = params_t + GG;

  // jax.random.split(key(42)) under threefry_partitionable:
  // child i = full 64-bit PRF output at counter (hi=0, lo=i).
  uint32_t k1a = 0, k1b = 0; tf2x32(0u, 42u, k1a, k1b);   // child 0
  uint32_t k2a = 0, k2b = 1; tf2x32(0u, 42u, k2a, k2b);   // child 1

  argmax_kernel<<<dim3(2 * BB), dim3(256), 0, stream>>>(sim, idx_p, idx_i);
  mlp_kernel<<<dim3(2 * MBLK), dim3(256), 0, stream>>>(
      post, image, tW1, tb1, tW2, tb2, iW1, ib1, iW2, ib2, params_t, params_i);
  combine_kernel<<<dim3((2 * MM) / 256), dim3(256), 0, stream>>>(
      idx_p, idx_i, params_t, params_i, out, k1a, k1b, k2a, k2b);
}